// Round 1
// 78.128 us; speedup vs baseline: 1.0089x; 1.0089x over previous
//
#include <hip/hip_runtime.h>

// ---------------------------------------------------------------------------
// QnnFormerVQC: 4-qubit VQC, B=262144, fp32 in / fp32 out.
// Round 6: split the fused kernel. rocprof showed the fused kernel (~37us of
// the 78.8us graph; the other 41us is the harness's 256MiB poison fill at 82%
// HBM peak, already roofline) was latency-bound: the 16x16 circuit build is a
// ~340-deep serial ds_swizzle chain, rebuilt redundantly by all 512 blocks at
// only 2 waves/SIMD. Now:
//   - qnn_prep (1 block, 256 thr): verified shuffle circuit builds U once,
//     stores Upack[512] floats to d_ws. Tiny code (~2KB), no icache issue.
//   - qnn_main (512 blocks): loads 8 floats/lane of U from global (L2
//     broadcast), then the verified readlane->SGPR FMA matvec + observables.
//     No LDS, no __syncthreads, no shuffle chain.
// Circuit semantics identical to the round-4/5 verified literal sequence
// (incl. the reference's _apmcx quirk: swap amps 7<->15, NOT 14<->15).
// ---------------------------------------------------------------------------

#define RL(x, l) __int_as_float(__builtin_amdgcn_readlane(__float_as_int(x), (l)))

// --- shuffle-gate helpers: lane holds one amplitude (ar,ai) of one column ---

// RX(theta): [[c,-is],[-is,c]] — same row formula for both halves.
__device__ __forceinline__ void g_rx(float& ar, float& ai, int amp, int m,
                                     float c, float s, int cmask) {
    const float br = __shfl_xor(ar, 1 << m, 64);
    const float bi = __shfl_xor(ai, 1 << m, 64);
    const float nr = c * ar + s * bi;
    const float ni = c * ai - s * br;
    const bool act = (amp & cmask) == cmask;
    ar = act ? nr : ar;
    ai = act ? ni : ai;
}

// RY(theta): [[c,-s],[s,c]] real.
__device__ __forceinline__ void g_ry(float& ar, float& ai, int amp, int m,
                                     float c, float s) {
    const float br = __shfl_xor(ar, 1 << m, 64);
    const float bi = __shfl_xor(ai, 1 << m, 64);
    const float sp = ((amp >> m) & 1) ? s : -s;
    ar = c * ar + sp * br;
    ai = c * ai + sp * bi;
}

// RZ(theta): diag(e^{-i t/2}, e^{+i t/2}) — no shuffle.
__device__ __forceinline__ void g_rz(float& ar, float& ai, int amp, int m,
                                     float c, float s) {
    const float p = ((amp >> m) & 1) ? s : -s;
    const float nr = c * ar - p * ai;
    const float ni = c * ai + p * ar;
    ar = nr; ai = ni;
}

// Hadamard.
__device__ __forceinline__ void g_h(float& ar, float& ai, int amp, int m) {
    const float R = 0.70710678118654752440f;
    const float br = __shfl_xor(ar, 1 << m, 64);
    const float bi = __shfl_xor(ai, 1 << m, 64);
    const bool hi = (amp >> m) & 1;
    ar = hi ? R * (br - ar) : R * (ar + br);
    ai = hi ? R * (bi - ai) : R * (ai + bi);
}

// X / CX / MCX: take partner's value when active.
__device__ __forceinline__ void g_swap(float& ar, float& ai, int m, bool act) {
    const float br = __shfl_xor(ar, 1 << m, 64);
    const float bi = __shfl_xor(ai, 1 << m, 64);
    ar = act ? br : ar;
    ai = act ? bi : ai;
}

// --- observables from psi (verified in round 4) ---
__device__ __forceinline__ void emit_obs(const float* pr, const float* pi,
                                         float* __restrict__ out, int b) {
    float n[16];
#pragma unroll
    for (int i = 0; i < 16; ++i) n[i] = pr[i] * pr[i] + pi[i] * pi[i];
    float o[12];
#pragma unroll
    for (int q = 0; q < 4; ++q) {
        const int m = 3 - q;
        const int mask = 1 << m;
        float z = 0.f, cr = 0.f, ci = 0.f;
#pragma unroll
        for (int p = 0; p < 8; ++p) {
            const int i0 = ((p >> m) << (m + 1)) | (p & (mask - 1));
            const int i1 = i0 | mask;
            z  += n[i0] - n[i1];
            cr += pr[i0] * pr[i1] + pi[i0] * pi[i1];
            ci += pr[i0] * pi[i1] - pi[i0] * pr[i1];
        }
        o[q]     = z;
        o[4 + q] = 2.f * cr;
        o[8 + q] = 2.f * ci;
    }
    float4* op = reinterpret_cast<float4*>(out + (size_t)b * 12);
    op[0] = make_float4(o[0], o[1], o[2],  o[3]);
    op[1] = make_float4(o[4], o[5], o[6],  o[7]);
    op[2] = make_float4(o[8], o[9], o[10], o[11]);
}

// ---------------------------------------------------------------------------
// Prep: ONE block builds the 16x16 circuit unitary, writes Upack to global.
// ---------------------------------------------------------------------------
__global__ __launch_bounds__(256)
void qnn_prep(const float* __restrict__ W,  const float* __restrict__ E,
              const float* __restrict__ G,  const float* __restrict__ Bt,
              float* __restrict__ Uout) {
    __shared__ float2 cs[30];      // (cos,sin) of half-angles of all params

    const int tid = threadIdx.x;

    // --- stage 0: 30 threads compute all parameter sincos once ---
    if (tid < 30) {
        float th;
        if (tid < 12)      th = W[tid];
        else if (tid < 24) th = E[tid - 12];
        else if (tid < 27) th = G[tid - 24];
        else               th = Bt[tid - 27];
        float s, c;
        __sincosf(0.5f * th, &s, &c);
        cs[tid] = make_float2(c, s);
    }
    __syncthreads();

    // --- stage 1: build U. thread = (col 0..15, amp 0..15); shfl partners
    //     share the same col since amp = lane&15. ---
    const int col = tid >> 4;
    const int amp = tid & 15;
    float ar = (amp == col) ? 1.f : 0.f;
    float ai = 0.f;

    for (int l = 0; l < 3; ++l) {
        // RX,RY,RZ (same angle weights[l][q]), qubit q -> bit 3-q
#pragma unroll
        for (int q = 0; q < 4; ++q) {
            const float2 cw = cs[l * 4 + q];
            g_rx(ar, ai, amp, 3 - q, cw.x, cw.y, 0);
            g_ry(ar, ai, amp, 3 - q, cw.x, cw.y);
            g_rz(ar, ai, amp, 3 - q, cw.x, cw.y);
        }
        // CRX chain: control i, target (i+1)%4
#pragma unroll
        for (int i = 0; i < 4; ++i) {
            const float2 ce = cs[12 + l * 4 + i];
            g_rx(ar, ai, amp, 3 - ((i + 1) & 3), ce.x, ce.y, 1 << (3 - i));
        }
        // H all, X all
#pragma unroll
        for (int q = 0; q < 4; ++q) g_h(ar, ai, amp, 3 - q);
#pragma unroll
        for (int q = 0; q < 4; ++q) g_swap(ar, ai, 3 - q, true);
        // H(q3), reference "MCX" = swap amps 7<->15, H(q3)
        g_h(ar, ai, amp, 0);
        g_swap(ar, ai, 3, (amp & 7) == 7);
        g_h(ar, ai, amp, 0);
        // X all, H all
#pragma unroll
        for (int q = 0; q < 4; ++q) g_swap(ar, ai, 3 - q, true);
#pragma unroll
        for (int q = 0; q < 4; ++q) g_h(ar, ai, amp, 3 - q);
        // CX(i,i+1) RZ(gamma on i+1) CX(i,i+1), i=0..2
        {
            const float2 cg = cs[24 + l];
#pragma unroll
            for (int i = 0; i < 3; ++i) {
                const int cm = 1 << (3 - i);
                const int m  = 2 - i;           // bit of qubit i+1
                g_swap(ar, ai, m, (amp & cm) == cm);
                g_rz(ar, ai, amp, m, cg.x, cg.y);
                g_swap(ar, ai, m, (amp & cm) == cm);
            }
        }
        // RX(beta) all
        {
            const float2 cb = cs[27 + l];
#pragma unroll
            for (int q = 0; q < 4; ++q) g_rx(ar, ai, amp, 3 - q, cb.x, cb.y, 0);
        }
    }

    // lane (col,amp) holds U[amp][col]; Upack layout: re at amp*32+2*col, im +1
    Uout[amp * 32 + 2 * col]     = ar;
    Uout[amp * 32 + 2 * col + 1] = ai;
}

// ---------------------------------------------------------------------------
// Main: pure matvec + observables. No LDS, no syncthreads, no shuffle chain.
// ---------------------------------------------------------------------------
__global__ __launch_bounds__(256, 2)
void qnn_main(const float* __restrict__ x, const float* __restrict__ Uin,
              float* __restrict__ out, int half) {
    const int tid  = threadIdx.x;
    const int lane = tid & 63;

    // batch indices first so x loads issue before/with the U loads
    const int b0 = blockIdx.x * 256 + tid;
    const int b1 = b0 + half;
    const float4 x0 = reinterpret_cast<const float4*>(x)[b0];
    const float4 x1 = reinterpret_cast<const float4*>(x)[b1];

    // each lane register-caches 8 floats of U (L2-broadcast, 2KB total)
    const float4 ua = reinterpret_cast<const float4*>(Uin)[2 * lane];
    const float4 ub = reinterpret_cast<const float4*>(Uin)[2 * lane + 1];
    const float u[8] = { ua.x, ua.y, ua.z, ua.w, ub.x, ub.y, ub.z, ub.w };

    float v0[16], v1[16];
    {
        float c0, s0, c1, s1, c2, s2, c3, s3;
        __sincosf(0.5f * x0.x, &s0, &c0);
        __sincosf(0.5f * x0.y, &s1, &c1);
        __sincosf(0.5f * x0.z, &s2, &c2);
        __sincosf(0.5f * x0.w, &s3, &c3);
        const float t01[4] = { c0 * c1, c0 * s1, s0 * c1, s0 * s1 };
        const float t23[4] = { c2 * c3, c2 * s3, s2 * c3, s2 * s3 };
#pragma unroll
        for (int i = 0; i < 16; ++i) v0[i] = t01[i >> 2] * t23[i & 3];
    }
    {
        float c0, s0, c1, s1, c2, s2, c3, s3;
        __sincosf(0.5f * x1.x, &s0, &c0);
        __sincosf(0.5f * x1.y, &s1, &c1);
        __sincosf(0.5f * x1.z, &s2, &c2);
        __sincosf(0.5f * x1.w, &s3, &c3);
        const float t01[4] = { c0 * c1, c0 * s1, s0 * c1, s0 * s1 };
        const float t23[4] = { c2 * c3, c2 * s3, s2 * c3, s2 * s3 };
#pragma unroll
        for (int i = 0; i < 16; ++i) v1[i] = t01[i >> 2] * t23[i & 3];
    }

    // psi = U v for both elements; coefficients via readlane -> SGPR FMA
    float pr0[16], pi0[16], pr1[16], pi1[16];
#pragma unroll
    for (int i = 0; i < 16; ++i) {
        float a0r = 0.f, a0i = 0.f, a1r = 0.f, a1i = 0.f;
#pragma unroll
        for (int j = 0; j < 16; ++j) {
            const int f = i * 32 + 2 * j;
            const float sUr = RL(u[f & 7], f >> 3);
            const float sUi = RL(u[(f & 7) + 1], f >> 3);
            a0r = fmaf(sUr, v0[j], a0r);
            a0i = fmaf(sUi, v0[j], a0i);
            a1r = fmaf(sUr, v1[j], a1r);
            a1i = fmaf(sUi, v1[j], a1i);
        }
        pr0[i] = a0r; pi0[i] = a0i;
        pr1[i] = a1r; pi1[i] = a1i;
    }

    emit_obs(pr0, pi0, out, b0);
    emit_obs(pr1, pi1, out, b1);
}

extern "C" void kernel_launch(void* const* d_in, const int* in_sizes, int n_in,
                              void* d_out, int out_size, void* d_ws, size_t ws_size,
                              hipStream_t stream) {
    const float* x  = (const float*)d_in[0];
    const float* W  = (const float*)d_in[1];
    const float* E  = (const float*)d_in[2];
    const float* G  = (const float*)d_in[3];
    const float* Bt = (const float*)d_in[4];
    float* out = (float*)d_out;
    float* Uws = (float*)d_ws;           // 512 floats = 2KB of workspace
    (void)ws_size; (void)n_in; (void)out_size;

    const int B = in_sizes[0] / 4;       // 262144
    const int half = B / 2;              // 2 elements per thread
    const int blocks = half / 256;       // 512

    hipLaunchKernelGGL(qnn_prep, dim3(1), dim3(256), 0, stream,
                       W, E, G, Bt, Uws);
    hipLaunchKernelGGL(qnn_main, dim3(blocks), dim3(256), 0, stream,
                       x, Uws, out, half);
}